// Round 8
// baseline (828.591 us; speedup 1.0000x reference)
//
#include <hip/hip_runtime.h>

typedef unsigned short ushort;
typedef __attribute__((ext_vector_type(8))) unsigned short ushort8;
typedef __attribute__((ext_vector_type(4))) unsigned short ushort4v;
typedef __attribute__((ext_vector_type(8))) short bf16x8;
typedef __attribute__((ext_vector_type(4))) float f32x4;

__device__ __forceinline__ float bf2f(ushort u) {
  union { unsigned int i; float f; } v; v.i = ((unsigned int)u) << 16; return v.f;
}
__device__ __forceinline__ ushort f2bf(float f) {
  union { float f; unsigned int i; } v; v.f = f;
  unsigned int x = v.i;
  return (ushort)((x + 0x7fffu + ((x >> 16) & 1u)) >> 16);
}
__device__ __forceinline__ float sigm(float x) { return 1.f / (1.f + __expf(-x)); }

// ---------------------------------------------------------------------------
// pack 6 weight matrices [2][768][256] f32 -> MFMA B-frag order bf16:
// elem = ((((mat*2+dir)*48 + ntAll)*8 + ks)*64 + l)*8 + e
//      = W[mat][dir][g = ntAll*16 + (l&15)][k = ks*32 + (l>>4)*8 + e]
// ---------------------------------------------------------------------------
__global__ __launch_bounds__(256) void pack_mfma(
    const float* __restrict__ s0, const float* __restrict__ s1,
    const float* __restrict__ s2, const float* __restrict__ s3,
    const float* __restrict__ s4, const float* __restrict__ s5,
    ushort* __restrict__ dst) {
  const float* srcs[6] = {s0, s1, s2, s3, s4, s5};
  int gid = blockIdx.x * 256 + threadIdx.x;  // 294912 total
  int mat = gid / 49152;
  int rem = gid - mat * 49152;
  int dir = rem / 24576;
  int rem2 = rem - dir * 24576;
  int nt = rem2 / 512;
  int rem3 = rem2 - nt * 512;
  int ks = rem3 >> 6;
  int l = rem3 & 63;
  int g = nt * 16 + (l & 15);
  int k0 = ks * 32 + (l >> 4) * 8;
  const float* sp = srcs[mat] + ((size_t)dir * 768 + g) * 256 + k0;
  ushort8 o;
#pragma unroll
  for (int e = 0; e < 8; ++e) o[e] = f2bf(sp[e]);
  *(ushort8*)(dst + (size_t)gid * 8) = o;
}

// emb f32 [30000*256] -> bf16
__global__ __launch_bounds__(256) void embcvt(const float* __restrict__ src,
                                              ushort* __restrict__ dst) {
  int i = blockIdx.x * 256 + threadIdx.x;  // 960000 vecs of 8
  if (i >= 960000) return;
  const float4* s = (const float4*)(src + (size_t)i * 8);
  float4 a = s[0], b = s[1];
  ushort8 o;
  o[0] = f2bf(a.x); o[1] = f2bf(a.y); o[2] = f2bf(a.z); o[3] = f2bf(a.w);
  o[4] = f2bf(b.x); o[5] = f2bf(b.y); o[6] = f2bf(b.z); o[7] = f2bf(b.w);
  *(ushort8*)(dst + (size_t)i * 8) = o;
}

// bf16 + bf16 -> bf16 (8-wide)
__global__ __launch_bounds__(256) void sum2bb(const ushort* __restrict__ a,
                                              const ushort* __restrict__ b,
                                              ushort* __restrict__ o, int nvec) {
  int i = blockIdx.x * 256 + threadIdx.x;
  if (i >= nvec) return;
  ushort8 va = *(const ushort8*)(a + (size_t)i * 8);
  ushort8 vb = *(const ushort8*)(b + (size_t)i * 8);
  ushort8 r;
#pragma unroll
  for (int e = 0; e < 8; ++e) r[e] = f2bf(bf2f(va[e]) + bf2f(vb[e]));
  *(ushort8*)(o + (size_t)i * 8) = r;
}

// f32 + f32 -> bf16 (8-wide)
__global__ __launch_bounds__(256) void sum2fb(const float* __restrict__ a,
                                              const float* __restrict__ b,
                                              ushort* __restrict__ o, int nvec) {
  int i = blockIdx.x * 256 + threadIdx.x;
  if (i >= nvec) return;
  const float4* pa = (const float4*)(a + (size_t)i * 8);
  const float4* pb = (const float4*)(b + (size_t)i * 8);
  float4 a0 = pa[0], a1 = pa[1], b0 = pb[0], b1 = pb[1];
  ushort8 r;
  r[0] = f2bf(a0.x + b0.x); r[1] = f2bf(a0.y + b0.y);
  r[2] = f2bf(a0.z + b0.z); r[3] = f2bf(a0.w + b0.w);
  r[4] = f2bf(a1.x + b1.x); r[5] = f2bf(a1.y + b1.y);
  r[6] = f2bf(a1.z + b1.z); r[7] = f2bf(a1.w + b1.w);
  *(ushort8*)(o + (size_t)i * 8) = r;
}

// ---------------------------------------------------------------------------
// gx GEMM: C[row'][col'] = sum_k A[src(row')][k] * W[col'][k], written in
// per-16x16-tile C-frag lane order: gx[dir][tid_m][tid_n][lane][rr] (ushort).
// row' is t-major: t = row'/NPAD, n = row'%NPAD + noff.
// Stores are REGULAR (not nontemporal): gx (<=201MB) + emb (15MB) fit L3,
// and gru_rec reads the stream immediately after.
// ---------------------------------------------------------------------------
template <int MODE>
__global__ __launch_bounds__(256) void gemm_gx(
    const ushort* __restrict__ A, const int* __restrict__ idx,
    const ushort* __restrict__ B, ushort* __restrict__ gx,
    int NPAD, int NSEQ, int T, int noff, int TMloc) {
  __shared__ __align__(16) ushort sa[128 * 32];
  const int tid = threadIdx.x;
  const int bm = blockIdx.x, bn = blockIdx.y;
  const int w = tid >> 6, l = tid & 63;
  const int wr = w >> 1, wc = w & 1;
  const int l15 = l & 15, lc = l >> 4;

  const int srow = tid >> 1;
  const int c0 = (tid & 1) * 2;
  int rloc = bm * 128 + srow;
  int t = rloc / NPAD;
  int nl = rloc - t * NPAD;
  int n = nl + noff;
  int grow;
  if (MODE == 0) grow = idx[n * T + t];
  else { int nn = n < NSEQ ? n : NSEQ - 1; grow = nn * T + t; }
  const ushort* srcrow = A + (size_t)grow * 256;

  const ushort* bbase[4];
#pragma unroll
  for (int i = 0; i < 4; ++i) {
    int ct = bn * 8 + wc * 4 + i;
    int dir = ct / 48;
    int ntAll = ct - dir * 48;
    bbase[i] = B + ((size_t)(dir * 48 + ntAll) * 8) * 512 + l * 8;
  }

  f32x4 acc[4][4];
#pragma unroll
  for (int mt = 0; mt < 4; ++mt)
#pragma unroll
    for (int nt = 0; nt < 4; ++nt) acc[mt][nt] = (f32x4){0.f, 0.f, 0.f, 0.f};

  ushort8 sta[2];
  bf16x8 bcur[4], bnxt[4];
#pragma unroll
  for (int j = 0; j < 2; ++j)
    sta[j] = *(const ushort8*)(srcrow + (c0 + j) * 8);
#pragma unroll
  for (int i = 0; i < 4; ++i) bcur[i] = *(const bf16x8*)(bbase[i]);

#pragma unroll
  for (int kk = 0; kk < 8; ++kk) {
    __syncthreads();
    *(ushort8*)(sa + srow * 32 + ((c0 + 0) ^ (srow & 3)) * 8) = sta[0];
    *(ushort8*)(sa + srow * 32 + ((c0 + 1) ^ (srow & 3)) * 8) = sta[1];
    __syncthreads();
    if (kk < 7) {
#pragma unroll
      for (int j = 0; j < 2; ++j)
        sta[j] = *(const ushort8*)(srcrow + (kk + 1) * 32 + (c0 + j) * 8);
#pragma unroll
      for (int i = 0; i < 4; ++i)
        bnxt[i] = *(const bf16x8*)(bbase[i] + (kk + 1) * 512);
    }
    bf16x8 af[4];
#pragma unroll
    for (int mt = 0; mt < 4; ++mt) {
      int row = wr * 64 + mt * 16 + l15;
      af[mt] = *(const bf16x8*)(sa + row * 32 + (lc ^ (row & 3)) * 8);
    }
#pragma unroll
    for (int mt = 0; mt < 4; ++mt)
#pragma unroll
      for (int nt = 0; nt < 4; ++nt)
        acc[mt][nt] = __builtin_amdgcn_mfma_f32_16x16x32_bf16(af[mt], bcur[nt],
                                                              acc[mt][nt], 0, 0, 0);
#pragma unroll
    for (int i = 0; i < 4; ++i) bcur[i] = bnxt[i];
  }

#pragma unroll
  for (int mt = 0; mt < 4; ++mt) {
    int tid_m = bm * 8 + wr * 4 + mt;
#pragma unroll
    for (int nt = 0; nt < 4; ++nt) {
      int ct = bn * 8 + wc * 4 + nt;
      int dir = ct / 48;
      int tid_n = ct - dir * 48;
      ushort4v o;
      o[0] = f2bf(acc[mt][nt][0]); o[1] = f2bf(acc[mt][nt][1]);
      o[2] = f2bf(acc[mt][nt][2]); o[3] = f2bf(acc[mt][nt][3]);
      *(ushort4v*)(gx + (((size_t)dir * TMloc + tid_m) * 48 + tid_n) * 256 + l * 4) = o;
    }
  }
}

// ---------------------------------------------------------------------------
// Unified recurrent GRU kernel: 512 thr = 8 waves, 16 rows/block, one
// direction per block (dir = bid&1, rowgroup = bid>>1).  r,z Whh fragments
// cached in 128 VGPRs (loaded once); n-gate streamed from L2 each step.
// h double-buffered in LDS -> ONE raw s_barrier per step (lgkmcnt drained
// only; gx global loads stay in flight across it).
// gx DEPTH-1-AHEAD PREFETCH: double-buffered gq register sets (named A/B,
// loop unrolled x2 -- no runtime indexing), loads for t+1 issued before
// step t's barrier => ~1.8 steps of HBM latency cover.
// ---------------------------------------------------------------------------
template <bool OUTF32>
__global__ __launch_bounds__(512) void gru_rec(
    const ushort* __restrict__ gx, const ushort* __restrict__ pWhh,
    const float* __restrict__ bih, const float* __restrict__ bhh,
    void* __restrict__ out_, int T, int NSEQ, int TPT, int TMloc, int noff) {
  __shared__ __align__(16) char shp[2][16 * 512];
  const int tid = threadIdx.x;
  const int w = tid >> 6, l = tid & 63;
  const int l15 = l & 15, lc = l >> 4;
  const int hi4 = lc << 2;
  const int dir = blockIdx.x & 1;
  const int rg = blockIdx.x >> 1;

  float bR[2], bZ[2], bNX[2], bNH[2];
#pragma unroll
  for (int q = 0; q < 2; ++q) {
    int jj = (2 * w + q) * 16 + l15;
    bR[q] = bih[dir * 768 + jj] + bhh[dir * 768 + jj];
    bZ[q] = bih[dir * 768 + 256 + jj] + bhh[dir * 768 + 256 + jj];
    bNX[q] = bih[dir * 768 + 512 + jj];
    bNH[q] = bhh[dir * 768 + 512 + jj];
  }
  const ushort* ph = pWhh + (size_t)dir * 196608;
  const size_t gxd = (size_t)dir * TMloc * 48 * 256;

  // cache r,z weight fragments (128 VGPR)
  bf16x8 wR[2][8], wZ[2][8];
#pragma unroll
  for (int q = 0; q < 2; ++q)
#pragma unroll
    for (int ks = 0; ks < 8; ++ks) {
      const ushort* pb = ph + (((2 * w + q) * 8 + ks) * 512) + l * 8;
      wR[q][ks] = *(const bf16x8*)(pb);
      wZ[q][ks] = *(const bf16x8*)(pb + 65536);
    }

  float hreg[2][4];
#pragma unroll
  for (int q = 0; q < 2; ++q)
#pragma unroll
    for (int r = 0; r < 4; ++r) hreg[q][r] = 0.f;

  // gx fetch for time step ts into dst (regular loads: want L3 hits)
  auto gxload = [&](ushort4v (&dst)[2][3], int ts) {
    const int tt = dir ? (T - 1 - ts) : ts;
    const int tile = tt * TPT + rg;
#pragma unroll
    for (int q = 0; q < 2; ++q)
#pragma unroll
      for (int g = 0; g < 3; ++g)
        dst[q][g] = *(const ushort4v*)(
            gx + gxd + ((size_t)tile * 48 + g * 16 + 2 * w + q) * 256 + l * 4);
  };

  // one time step: prefetch gx for tnext into nxt, compute with cur
  auto step = [&](int t, ushort4v (&cur)[2][3], ushort4v (&nxt)[2][3], char* hb) {
    const int tnext = (t + 1 < T) ? (t + 1) : (T - 1);
    gxload(nxt, tnext);

    // write h(t-1) into this parity's buffer (zeros at t=0 handled by hreg)
#pragma unroll
    for (int q = 0; q < 2; ++q)
#pragma unroll
      for (int r = 0; r < 4; ++r) {
        int i = hi4 + r;
        int jj = (2 * w + q) * 16 + l15;
        *(ushort*)(hb + i * 512 + ((jj * 2) ^ (i << 4))) = f2bf(hreg[q][r]);
      }
    asm volatile("s_waitcnt lgkmcnt(0)" ::: "memory");
    __builtin_amdgcn_s_barrier();
    __builtin_amdgcn_sched_barrier(0);

    f32x4 aR[2], aZ[2], aNH[2];
#pragma unroll
    for (int q = 0; q < 2; ++q) {
      aR[q] = (f32x4){bR[q], bR[q], bR[q], bR[q]};
      aZ[q] = (f32x4){bZ[q], bZ[q], bZ[q], bZ[q]};
      aNH[q] = (f32x4){bNH[q], bNH[q], bNH[q], bNH[q]};
    }
#pragma unroll
    for (int ks = 0; ks < 8; ++ks) {
      bf16x8 af = *(const bf16x8*)(hb + l15 * 512 + ((ks * 64 + lc * 16) ^ (l15 << 4)));
#pragma unroll
      for (int q = 0; q < 2; ++q) {
        bf16x8 bNw = *(const bf16x8*)(ph + 131072 + (((2 * w + q) * 8 + ks) * 512) + l * 8);
        aR[q] = __builtin_amdgcn_mfma_f32_16x16x32_bf16(af, wR[q][ks], aR[q], 0, 0, 0);
        aZ[q] = __builtin_amdgcn_mfma_f32_16x16x32_bf16(af, wZ[q][ks], aZ[q], 0, 0, 0);
        aNH[q] = __builtin_amdgcn_mfma_f32_16x16x32_bf16(af, bNw, aNH[q], 0, 0, 0);
      }
    }
#pragma unroll
    for (int q = 0; q < 2; ++q)
#pragma unroll
      for (int r = 0; r < 4; ++r) {
        float rr = sigm(aR[q][r] + bf2f(cur[q][0][r]));
        float zz = sigm(aZ[q][r] + bf2f(cur[q][1][r]));
        float nv = bf2f(cur[q][2][r]) + bNX[q] + rr * aNH[q][r];
        float e2 = __expf(-2.f * nv);
        float nn = (1.f - e2) / (1.f + e2);
        hreg[q][r] = (1.f - zz) * nn + zz * hreg[q][r];
      }
  };

  ushort4v gqA[2][3], gqB[2][3];
  gxload(gqA, 0);
  for (int t2 = 0; t2 < T; t2 += 2) {  // T is even (32 or 16)
    step(t2,     gqA, gqB, shp[0]);
    step(t2 + 1, gqB, gqA, shp[1]);
  }

#pragma unroll
  for (int q = 0; q < 2; ++q)
#pragma unroll
    for (int r = 0; r < 4; ++r) {
      int i = hi4 + r;
      int gn = noff + rg * 16 + i;
      if (gn < NSEQ) {
        int jj = (2 * w + q) * 16 + l15;
        size_t off = (size_t)dir * NSEQ * 256 + (size_t)gn * 256 + jj;
        if (OUTF32) ((float*)out_)[off] = hreg[q][r];
        else ((ushort*)out_)[off] = f2bf(hreg[q][r]);
      }
    }
}

// ---------------------------------------------------------------------------
// FC heads (validated R2/R3)
// ---------------------------------------------------------------------------
__global__ __launch_bounds__(128) void fc_head(
    const float* __restrict__ revf, const float* __restrict__ revb,
    const float* __restrict__ bizf, const float* __restrict__ bizb,
    const float* __restrict__ rW1, const float* __restrict__ rb1,
    const float* __restrict__ rW2, const float* __restrict__ rb2,
    const float* __restrict__ pW1, const float* __restrict__ pb1,
    const float* __restrict__ pW2, const float* __restrict__ pb2,
    float* __restrict__ out) {
  const int b = blockIdx.x;
  const int tid = threadIdx.x;
  const float *xf, *xb2, *W1, *b1, *W2, *b2;
  float* o;
  if (b < 128) {
    xf = revf + (size_t)b * 256; xb2 = revb + (size_t)b * 256;
    W1 = rW1; b1 = rb1; W2 = rW2; b2 = rb2; o = out + 8 + b;
  } else {
    int bb = b - 128;
    xf = bizf + (size_t)bb * 256; xb2 = bizb + (size_t)bb * 256;
    W1 = pW1; b1 = pb1; W2 = pW2; b2 = pb2; o = out + bb;
  }
  float acc = 0.f;
  const float4* f4 = (const float4*)xf;
  const float4* g4 = (const float4*)xb2;
  const float4* w4 = (const float4*)(W1 + (size_t)tid * 256);
#pragma unroll 4
  for (int k = 0; k < 64; ++k) {
    float4 a = f4[k], g = g4[k], w = w4[k];
    acc = fmaf(a.x + g.x, w.x, fmaf(a.y + g.y, w.y,
          fmaf(a.z + g.z, w.z, fmaf(a.w + g.w, w.w, acc))));
  }
  acc += b1[tid];
  const float LAM = 1.0507009873554805f, ALPHA = 1.6732632423543772f;
  float h = acc > 0.f ? LAM * acc : LAM * ALPHA * (__expf(acc) - 1.f);
  __shared__ float p[128];
  p[tid] = h * W2[tid];
  __syncthreads();
  if (tid == 0) {
    float s = b2[0];
#pragma unroll 8
    for (int i = 0; i < 128; ++i) s += p[i];
    *o = s;
  }
}

extern "C" void kernel_launch(void* const* d_in, const int* in_sizes, int n_in,
                              void* d_out, int out_size, void* d_ws, size_t ws_size,
                              hipStream_t stream) {
  const int*   inputs = (const int*)d_in[0];
  const float* emb    = (const float*)d_in[1];
  const float* w_Wih  = (const float*)d_in[2];
  const float* w_Whh  = (const float*)d_in[3];
  const float* w_bih  = (const float*)d_in[4];
  const float* w_bhh  = (const float*)d_in[5];
  const float* s_Wih  = (const float*)d_in[6];
  const float* s_Whh  = (const float*)d_in[7];
  const float* s_bih  = (const float*)d_in[8];
  const float* s_bhh  = (const float*)d_in[9];
  const float* r_Wih  = (const float*)d_in[10];
  const float* r_Whh  = (const float*)d_in[11];
  const float* r_bih  = (const float*)d_in[12];
  const float* r_bhh  = (const float*)d_in[13];
  const float* rfc_W1 = (const float*)d_in[14];
  const float* rfc_b1 = (const float*)d_in[15];
  const float* rfc_W2 = (const float*)d_in[16];
  const float* rfc_b2 = (const float*)d_in[17];
  const float* pfc_W1 = (const float*)d_in[18];
  const float* pfc_b1 = (const float*)d_in[19];
  const float* pfc_W2 = (const float*)d_in[20];
  const float* pfc_b2 = (const float*)d_in[21];
  float* out = (float*)d_out;

  char* ws = (char*)d_ws;
  ushort* pmf    = (ushort*)(ws);                    //  4,718,592
  ushort* embb   = (ushort*)(ws + 4718592);          // 15,360,000
  ushort* sentA  = (ushort*)(ws + 20078592);         //  1,048,576
  ushort* sent_f = (ushort*)(ws + 21127168);         //  2,097,152 (both dirs)
  float*  rev_f  = (float*)(ws + 23224320);          //    262,144 (both dirs)
  ushort* revsum = (ushort*)(ws + 23486464);         //     65,536
  float*  biz_f  = (float*)(ws + 23552000);          //     16,384
  ushort* gxs    = (ushort*)(ws + 23568384);         //  6,291,456
  ushort* gxr    = (ushort*)(ws + 29859840);         //    786,432
  ushort* gxw    = (ushort*)(ws + 30646272);         // up to 201,326,592
  float* rev_b = rev_f + 32768;
  float* biz_b = biz_f + 2048;
  ushort* sent_b = sent_f + 524288;

  const size_t gx_full = 201326592ull;
  const size_t fixed_end = 30646272ull;
  int NP = 32;
  for (int cand = 1; cand <= 32; cand <<= 1) {
    if (ws_size >= fixed_end + gx_full / cand) { NP = cand; break; }
  }
  const int slice = 2048 / NP;
  const int TMp = 4096 / NP;

  embcvt<<<3750, 256, 0, stream>>>(emb, embb);
  pack_mfma<<<1152, 256, 0, stream>>>(w_Wih, w_Whh, s_Wih, s_Whh, r_Wih, r_Whh, pmf);

  // word level (per pass: gx GEMM then recurrent; 256 blocks/pass at NP=1)
  for (int p = 0; p < NP; ++p) {
    gemm_gx<0><<<dim3(512 / NP, 12), 256, 0, stream>>>(
        embb, inputs, pmf, gxw, slice, 2048, 32, p * slice, TMp);
    gru_rec<false><<<(slice / 16) * 2, 512, 0, stream>>>(
        gxw, pmf + 393216, w_bih, w_bhh, sent_f, 32, 2048, slice / 16, TMp, p * slice);
  }
  sum2bb<<<256, 256, 0, stream>>>(sent_f, sent_b, sentA, 65536);

  // sentence level
  gemm_gx<1><<<dim3(16, 12), 256, 0, stream>>>(
      sentA, nullptr, pmf + 2 * 393216, gxs, 128, 128, 16, 0, 128);
  gru_rec<true><<<16, 512, 0, stream>>>(gxs, pmf + 3 * 393216, s_bih, s_bhh,
                                        rev_f, 16, 128, 8, 128, 0);
  sum2fb<<<16, 256, 0, stream>>>(rev_f, rev_b, revsum, 4096);

  // review level (rows padded 8->16)
  gemm_gx<1><<<dim3(2, 12), 256, 0, stream>>>(
      revsum, nullptr, pmf + 4 * 393216, gxr, 16, 8, 16, 0, 16);
  gru_rec<true><<<2, 512, 0, stream>>>(gxr, pmf + 5 * 393216, r_bih, r_bhh,
                                       biz_f, 16, 8, 1, 16, 0);

  fc_head<<<136, 128, 0, stream>>>(rev_f, rev_b, biz_f, biz_b,
                                   rfc_W1, rfc_b1, rfc_W2, rfc_b2,
                                   pfc_W1, pfc_b1, pfc_W2, pfc_b2, out);
}